// Round 11
// baseline (689.551 us; speedup 1.0000x reference)
//
#include <hip/hip_runtime.h>

#define NNODES 100000
#define NEDGES 800000
#define NTILE128 782            // ceil(100000/128)
#define NROWPAD (NTILE128*128)  // 100096 padded rows in ws planes
#define NBKT 782                // dst buckets of 128 nodes

typedef _Float16 f16x8 __attribute__((ext_vector_type(8)));
typedef float    f32x4 __attribute__((ext_vector_type(4)));
typedef unsigned int u32;
typedef unsigned short u16;

// ===========================================================================
// Bucketed CSR build (round-11): chist -> cscan -> fill1 -> fill2
// Replaces 100k-counter hist + 3 scans + random-scatter fill (write-amp 18x).
// ===========================================================================
__global__ __launch_bounds__(256) void chist_kernel(const int* __restrict__ dst,
                                                    int* __restrict__ cb, int nE) {
    int i = blockIdx.x * 256 + threadIdx.x;
    if (i < nE) atomicAdd(cb + (dst[i] >> 7), 1);
}

// scan 782 bucket counts -> cboff[783]; zero fill1 cursors
__global__ __launch_bounds__(1024) void cscan_kernel(const int* __restrict__ cb,
                                                     int* __restrict__ cboff,
                                                     int* __restrict__ ccur) {
    __shared__ int s[1024];
    int t = threadIdx.x;
    s[t] = (t < NBKT) ? cb[t] : 0;
    __syncthreads();
    for (int off = 1; off < 1024; off <<= 1) {
        int v = (t >= off) ? s[t - off] : 0;
        __syncthreads();
        s[t] += v;
        __syncthreads();
    }
    if (t < NBKT) {
        cboff[t + 1] = s[t];
        ccur[t] = 0;
    }
    if (t == 0) cboff[0] = 0;
}

// scatter edges into bucket-contiguous staging as (src<<7)|dstlo
__global__ __launch_bounds__(256) void fill1_kernel(const int* __restrict__ src,
                                                    const int* __restrict__ dst,
                                                    const int* __restrict__ cboff,
                                                    int* __restrict__ ccur,
                                                    u32* __restrict__ staged, int nE) {
    int i = blockIdx.x * 256 + threadIdx.x;
    if (i >= nE) return;
    int d = dst[i];
    int b = d >> 7;
    int p = atomicAdd(ccur + b, 1);
    staged[cboff[b] + p] = ((u32)src[i] << 7) | (u32)(d & 127);
}

// one block per bucket: LDS fine-sort -> rowptr + eidx (single-XCD writes)
__global__ __launch_bounds__(256) void fill2_kernel(const u32* __restrict__ staged,
                                                    const int* __restrict__ cboff,
                                                    int* __restrict__ rowptr,
                                                    int* __restrict__ eidx) {
    __shared__ int lcnt[128], lex[128], lcur[128];
    int b = blockIdx.x, t = threadIdx.x;
    int n0 = cboff[b], n1 = cboff[b + 1], cnt = n1 - n0;
    if (t < 128) { lcnt[t] = 0; lcur[t] = 0; }
    __syncthreads();
    for (int j = t; j < cnt; j += 256) atomicAdd(&lcnt[staged[n0 + j] & 127], 1);
    __syncthreads();
    if (t < 128) lex[t] = lcnt[t];
    __syncthreads();
    for (int off = 1; off < 128; off <<= 1) {
        int v = (t < 128 && t >= off) ? lex[t - off] : 0;
        __syncthreads();
        if (t < 128) lex[t] += v;
        __syncthreads();
    }
    if (t < 128) {
        int node = b * 128 + t;
        int ex = lex[t] - lcnt[t];
        if (node <= NNODES) rowptr[node] = n0 + ex;  // b=781,t=32 writes rowptr[N]=nE
        lex[t] = ex;
    }
    __syncthreads();
    for (int j = t; j < cnt; j += 256) {
        u32 v = staged[n0 + j];
        int dl = (int)(v & 127);
        int p = atomicAdd(&lcur[dl], 1);
        eidx[n0 + lex[dl] + p] = (int)(v >> 7);
    }
}

// ===========================================================================
// W pre-pack (round-10 proven): fp32 [N][128] -> fragment-ordered fp16
// ===========================================================================
__global__ __launch_bounds__(256) void wpack_kernel(const float* __restrict__ W1,
                                                    const float* __restrict__ W2,
                                                    const float* __restrict__ W3,
                                                    const float* __restrict__ Wo1,
                                                    const float* __restrict__ Wo2,
                                                    _Float16* __restrict__ wp) {
    int i = blockIdx.x * 256 + threadIdx.x;  // frag-group id, 0..9215
    if (i >= 9216) return;
    const float* Wm;
    int li;
    size_t base;
    if (i < 8192) {
        int m = i >> 11;
        li = i & 2047;
        Wm = (m == 0) ? W1 : (m == 1) ? W2 : (m == 2) ? W3 : Wo1;
        base = (size_t)m * 16384;
    } else {
        li = i - 8192;
        Wm = Wo2;
        base = 65536;
    }
    int lane = li & 63;
    int n = ((li >> 8) * 16) + (lane & 15);
    int k0 = (((li >> 6) & 3) * 32) + ((lane >> 4) * 8);
    const float* s = Wm + (size_t)n * 128 + k0;
    float4 a = *(const float4*)s;
    float4 b = *(const float4*)(s + 4);
    f16x8 v;
    v[0] = (_Float16)a.x; v[1] = (_Float16)a.y; v[2] = (_Float16)a.z; v[3] = (_Float16)a.w;
    v[4] = (_Float16)b.x; v[5] = (_Float16)b.y; v[6] = (_Float16)b.z; v[7] = (_Float16)b.w;
    *(f16x8*)(wp + base + (size_t)li * 8) = v;
}

// ===========================================================================
// Gather-mean + combine (round-8/9 proven): out = base + mean_nbr H[nbr].
// One wave/node; 8 edges in flight; 16 lanes x f16x8 per row.
// ===========================================================================
__global__ __launch_bounds__(256) void gather_kernel(const _Float16* __restrict__ H,
                                                     const int* __restrict__ rowptr,
                                                     const int* __restrict__ eidx,
                                                     _Float16* __restrict__ O, int n) {
    int node = blockIdx.x * 4 + (threadIdx.x >> 6);
    int lane = threadIdx.x & 63;
    if (node >= n) return;
    int g = lane >> 4, p = lane & 15;
    int e0 = rowptr[node], e1 = rowptr[node + 1];
    float acc[8] = {0.f, 0.f, 0.f, 0.f, 0.f, 0.f, 0.f, 0.f};
    for (int j = e0; j < e1; j += 8) {
        int na = e1 - j;
        int sid = (lane < 8 && lane < na) ? eidx[j + lane] : -1;
        int s0 = __shfl(sid, g);
        int s1 = __shfl(sid, g + 4);
        f16x8 v0, v1;
        bool h0 = (s0 >= 0), h1 = (s1 >= 0);
        if (h0) v0 = *(const f16x8*)(H + (size_t)s0 * 128 + p * 8);
        if (h1) v1 = *(const f16x8*)(H + (size_t)s1 * 128 + p * 8);
        if (h0) {
#pragma unroll
            for (int r = 0; r < 8; ++r) acc[r] += (float)v0[r];
        }
        if (h1) {
#pragma unroll
            for (int r = 0; r < 8; ++r) acc[r] += (float)v1[r];
        }
    }
#pragma unroll
    for (int r = 0; r < 8; ++r) {
        acc[r] += __shfl_xor(acc[r], 16);
        acc[r] += __shfl_xor(acc[r], 32);
    }
    if (g == 0) {
        float rinv = 1.0f / fmaxf((float)(e1 - e0), 1.0f);
        f16x8 b = *(const f16x8*)(H + (size_t)node * 128 + p * 8);
        f16x8 o;
#pragma unroll
        for (int r = 0; r < 8; ++r) o[r] = (_Float16)((float)b[r] + acc[r] * rinv);
        *(f16x8*)(O + (size_t)node * 128 + p * 8) = o;
    }
}

// ===========================================================================
// Fused GEMM chain (round-10 proven, unchanged).
// ===========================================================================
template <int S, bool INF32, bool OUTF32, int TL, bool R0, bool R1, bool R2>
__global__ __launch_bounds__(512, 2) void chain_kernel(
    const void* __restrict__ A_,
    const _Float16* __restrict__ wq0, const float* __restrict__ Bg0,
    const _Float16* __restrict__ wq1, const float* __restrict__ Bg1,
    const _Float16* __restrict__ wq2, const float* __restrict__ Bg2,
    _Float16* __restrict__ O, float* __restrict__ Of32) {
    __shared__ u32 ibuf[128][137];  // 70.1 KB
    const int tid = threadIdx.x;
    const int lane = tid & 63, w = tid >> 6;
    const int lm = lane & 15, g = lane >> 4;
    const int tile = blockIdx.x;

    f16x8 ah[4];
    const int arow = tile * 128 + w * 16 + lm;
    if (INF32) {
        const float* base = (const float*)A_ + (size_t)min(arow, NNODES - 1) * 128;
#pragma unroll
        for (int ks = 0; ks < 4; ++ks) {
            float4 a = *(const float4*)(base + ks * 32 + g * 8);
            float4 b = *(const float4*)(base + ks * 32 + g * 8 + 4);
            ah[ks][0] = (_Float16)a.x; ah[ks][1] = (_Float16)a.y;
            ah[ks][2] = (_Float16)a.z; ah[ks][3] = (_Float16)a.w;
            ah[ks][4] = (_Float16)b.x; ah[ks][5] = (_Float16)b.y;
            ah[ks][6] = (_Float16)b.z; ah[ks][7] = (_Float16)b.w;
        }
    } else {
        const _Float16* bp = (const _Float16*)A_ + (size_t)arow * 128;
#pragma unroll
        for (int ks = 0; ks < 4; ++ks) ah[ks] = *(const f16x8*)(bp + ks * 32 + g * 8);
    }

#pragma unroll
    for (int s = 0; s < S; ++s) {
        const _Float16* wq = (s == 0) ? wq0 : (s == 1) ? wq1 : wq2;
        const float* Bg = (s == 0) ? Bg0 : (s == 1) ? Bg1 : Bg2;
        const bool RELU = (s == 0) ? R0 : (s == 1) ? R1 : R2;
        const int T = (s == S - 1) ? TL : 8;

        f32x4 acc[8];
#pragma unroll
        for (int t = 0; t < 8; ++t)
            if (t < T) {
                float bv = Bg[t * 16 + lm];
                acc[t] = (f32x4){bv, bv, bv, bv};
            }
#pragma unroll
        for (int t = 0; t < 8; ++t)
            if (t < T) {
#pragma unroll
                for (int ks = 0; ks < 4; ++ks) {
                    f16x8 wv = *(const f16x8*)(wq + ((size_t)(t * 4 + ks) * 64 + lane) * 8);
                    acc[t] = __builtin_amdgcn_mfma_f32_16x16x32_f16(ah[ks], wv, acc[t], 0, 0, 0);
                }
            }

        if (s < S - 1) {
            __syncthreads();
            const int lrow0 = w * 16 + g * 4;
#pragma unroll
            for (int t = 0; t < 8; ++t)
#pragma unroll
                for (int r = 0; r < 4; ++r) {
                    float v = acc[t][r];
                    if (RELU) v = fmaxf(v, 0.f);
                    _Float16 h = (_Float16)v;
                    ibuf[lrow0 + r][t * 16 + lm] = (u32)(*(u16*)&h);
                }
            __syncthreads();
            const u32* rp = &ibuf[w * 16 + lm][0];
#pragma unroll
            for (int ks = 0; ks < 4; ++ks) {
                u32 v[8];
                *(f32x4*)v = *(const f32x4*)(rp + ks * 32 + g * 8);
                *(f32x4*)(v + 4) = *(const f32x4*)(rp + ks * 32 + g * 8 + 4);
#pragma unroll
                for (int j = 0; j < 8; ++j) {
                    u16 hs = (u16)(v[j] & 0xffffu);
                    ah[ks][j] = *(_Float16*)&hs;
                }
            }
        } else if (OUTF32) {
            const int mrow0 = tile * 128 + w * 16 + g * 4;
#pragma unroll
            for (int t = 0; t < TL; ++t) {
                const int n = t * 16 + lm;
#pragma unroll
                for (int r = 0; r < 4; ++r) {
                    float v = acc[t][r];
                    if (RELU) v = fmaxf(v, 0.f);
                    int m = mrow0 + r;
                    if (m < NNODES) Of32[(size_t)m * 64 + n] = v;
                }
            }
        } else {
            __syncthreads();
            const int lrow0 = w * 16 + g * 4;
#pragma unroll
            for (int t = 0; t < 8; ++t)
#pragma unroll
                for (int r = 0; r < 4; ++r) {
                    float v = acc[t][r];
                    if (RELU) v = fmaxf(v, 0.f);
                    _Float16 h = (_Float16)v;
                    ibuf[lrow0 + r][t * 16 + lm] = (u32)(*(u16*)&h);
                }
            __syncthreads();
#pragma unroll
            for (int pass = 0; pass < 4; ++pass) {
                int unit = pass * 512 + tid;
                int lrow = unit >> 4, c8 = unit & 15;
                const u32* p = &ibuf[lrow][c8 * 8];
                u32 v[8];
                *(f32x4*)v = *(const f32x4*)p;
                *(f32x4*)(v + 4) = *(const f32x4*)(p + 4);
                f16x8 hh;
#pragma unroll
                for (int j = 0; j < 8; ++j) {
                    u16 hs = (u16)(v[j] & 0xffffu);
                    hh[j] = *(_Float16*)&hs;
                }
                *(f16x8*)(O + (size_t)(tile * 128 + lrow) * 128 + c8 * 8) = hh;
            }
        }
    }
}

// ===========================================================================
extern "C" void kernel_launch(void* const* d_in, const int* in_sizes, int n_in,
                              void* d_out, int out_size, void* d_ws, size_t ws_size,
                              hipStream_t stream) {
    const float* x   = (const float*)d_in[0];
    const int*   src = (const int*)d_in[1];
    const int*   dst = (const int*)d_in[2];
    const float* W1  = (const float*)d_in[3];
    const float* b1  = (const float*)d_in[4];
    const float* W2  = (const float*)d_in[5];
    const float* b2  = (const float*)d_in[6];
    const float* W3  = (const float*)d_in[7];
    const float* b3  = (const float*)d_in[8];
    const float* Wo1 = (const float*)d_in[9];
    const float* bo1 = (const float*)d_in[10];
    const float* Wo2 = (const float*)d_in[11];
    const float* bo2 = (const float*)d_in[12];
    float* out = (float*)d_out;

    const size_t PLANE = (size_t)NROWPAD * 128 * sizeof(_Float16);  // 25.62 MB
    char* ws = (char*)d_ws;
    _Float16* P0 = (_Float16*)ws;
    _Float16* P1 = (_Float16*)(ws + PLANE);
    char* p = ws + 2 * PLANE;
    int* rowptr = (int*)p;        p += 512 * 1024;
    int* cb     = (int*)p;        p += 4 * 1024;
    int* cboff  = (int*)p;        p += 4 * 1024;
    int* ccur   = (int*)p;        p += 4 * 1024;
    _Float16* wp = (_Float16*)p;  p += 256 * 1024;  // 73728 elems packed
    u32* staged = (u32*)p;        p += (size_t)NEDGES * 4;  // 3.2 MB
    int* eidx   = (int*)p;        // 3.2 MB

    dim3 blk(256);
    const int ge = (NEDGES + 255) / 256;  // 3125
    const int gg = (NNODES + 3) / 4;      // 25000

    // ---- W pre-pack (once per call) ----
    wpack_kernel<<<36, blk, 0, stream>>>(W1, W2, W3, Wo1, Wo2, wp);

    // ---- bucketed CSR build ----
    hipMemsetAsync(cb, 0, NBKT * sizeof(int), stream);
    chist_kernel<<<ge, blk, 0, stream>>>(dst, cb, NEDGES);
    cscan_kernel<<<1, 1024, 0, stream>>>(cb, cboff, ccur);
    fill1_kernel<<<ge, blk, 0, stream>>>(src, dst, cboff, ccur, staged, NEDGES);
    fill2_kernel<<<NBKT, blk, 0, stream>>>(staged, cboff, rowptr, eidx);

    const _Float16 *q1 = wp, *q2 = wp + 16384, *q3 = wp + 32768,
                   *qo1 = wp + 49152, *qo2 = wp + 65536;

    // ---- chain A: x2 = lin2(relu(lin1(x))) ----
    chain_kernel<2, true, false, 8, true, false, false><<<NTILE128, 512, 0, stream>>>(
        x, q1, b1, q2, b2, nullptr, nullptr, P0, nullptr);

    // ---- h = x2 + mean_agg(x2) ----
    gather_kernel<<<gg, blk, 0, stream>>>(P0, rowptr, eidx, P1, NNODES);

    // ---- chain B: h3 = relu(lin3(lin2(relu(lin1(h))))) ----
    chain_kernel<3, false, false, 8, true, false, true><<<NTILE128, 512, 0, stream>>>(
        P1, q1, b1, q2, b2, q3, b3, P0, nullptr);

    // ---- h4 = h3 + mean_agg(h3) ----
    gather_kernel<<<gg, blk, 0, stream>>>(P0, rowptr, eidx, P1, NNODES);

    // ---- chain C: out = lino2(relu(lino1(relu(lin3(h4))))) ----
    chain_kernel<3, false, true, 4, true, true, false><<<NTILE128, 512, 0, stream>>>(
        P1, q3, b3, qo1, bo1, qo2, bo2, nullptr, out);
}